// Round 4
// baseline (28.358 us; speedup 1.0000x reference)
//
#include <hip/hip_runtime.h>

// Time2Vec: out[b,s, i*64+j] = (j==0) ? (x[b,s,i]*w[i,j]+b[i,j])
//                                     : sin(x[b,s,i]*w[i,j]+b[i,j])
// B=32, S=2048, D=8, E=64  ->  ROWS=65536 rows of 512 f32 outputs.
// Write-BW-bound: 134 MB out, 2 MB in. Round-3 lesson: nontemporal stores
// HURT (-4%) -> plain stores. This round: unroll x4, constant-stride
// addressing, exact trip count (no tail branch).

constexpr int D_IN  = 8;
constexpr int E_PER = 64;
constexpr int CHANS = D_IN * E_PER;      // 512
constexpr int ROWS  = 32 * 2048;         // 65536
constexpr int TOTAL = ROWS * CHANS;      // 33,554,432

typedef float vf4 __attribute__((ext_vector_type(4)));

// 2048 blocks x 256 threads = 524,288 threads; TOTAL/4 float4s / threads = 16
// iterations per thread -> 4 unrolled-by-4 iterations, no remainder.
constexpr int NTHREADS   = 2048 * 256;
constexpr int STRIDE_EL  = NTHREADS * 4;          // 2,097,152 elems = 4096 rows
constexpr int ROW_STRIDE = STRIDE_EL / CHANS;     // 4096 rows per step
constexpr int X_STRIDE   = ROW_STRIDE * D_IN;     // x-elems per step (32768)
constexpr int NITER      = TOTAL / (4 * STRIDE_EL);  // = 4

__global__ __launch_bounds__(256) void time2vec_kernel(
    const float* __restrict__ x,      // [ROWS, 8]
    const float* __restrict__ w,      // [8, 64]
    const float* __restrict__ b,      // [8, 64]
    float* __restrict__ out)          // [ROWS, 512]
{
    const int tid = blockIdx.x * blockDim.x + threadIdx.x;

    // Channel within the 512-wide row is loop-invariant for this thread.
    const int c = (tid * 4) & (CHANS - 1);
    const int i = c >> 6;        // input feature (0..7)
    const int j = c & 63;        // column within the 64-wide embed (mult of 4)

    const vf4 w4 = *reinterpret_cast<const vf4*>(w + i * E_PER + j);
    const vf4 b4 = *reinterpret_cast<const vf4*>(b + i * E_PER + j);
    const bool lin0 = (j == 0);

    // Base addresses; everything below advances by compile-time constants.
    const float* xp = x + (tid * 4 >> 9) * D_IN + i;   // this thread's x elem
    float*       op = out + tid * 4;

#pragma unroll
    for (int it = 0; it < NITER; ++it) {
        // 4 independent x loads in flight.
        const float x0 = xp[0 * X_STRIDE];
        const float x1 = xp[1 * X_STRIDE];
        const float x2 = xp[2 * X_STRIDE];
        const float x3 = xp[3 * X_STRIDE];

        vf4 r0, r1, r2, r3;
        {
            const float a0 = fmaf(x0, w4.x, b4.x);
            r0.x = lin0 ? a0 : __sinf(a0);
            r0.y = __sinf(fmaf(x0, w4.y, b4.y));
            r0.z = __sinf(fmaf(x0, w4.z, b4.z));
            r0.w = __sinf(fmaf(x0, w4.w, b4.w));
        }
        {
            const float a0 = fmaf(x1, w4.x, b4.x);
            r1.x = lin0 ? a0 : __sinf(a0);
            r1.y = __sinf(fmaf(x1, w4.y, b4.y));
            r1.z = __sinf(fmaf(x1, w4.z, b4.z));
            r1.w = __sinf(fmaf(x1, w4.w, b4.w));
        }
        {
            const float a0 = fmaf(x2, w4.x, b4.x);
            r2.x = lin0 ? a0 : __sinf(a0);
            r2.y = __sinf(fmaf(x2, w4.y, b4.y));
            r2.z = __sinf(fmaf(x2, w4.z, b4.z));
            r2.w = __sinf(fmaf(x2, w4.w, b4.w));
        }
        {
            const float a0 = fmaf(x3, w4.x, b4.x);
            r3.x = lin0 ? a0 : __sinf(a0);
            r3.y = __sinf(fmaf(x3, w4.y, b4.y));
            r3.z = __sinf(fmaf(x3, w4.z, b4.z));
            r3.w = __sinf(fmaf(x3, w4.w, b4.w));
        }

        *reinterpret_cast<vf4*>(op + 0 * STRIDE_EL) = r0;
        *reinterpret_cast<vf4*>(op + 1 * STRIDE_EL) = r1;
        *reinterpret_cast<vf4*>(op + 2 * STRIDE_EL) = r2;
        *reinterpret_cast<vf4*>(op + 3 * STRIDE_EL) = r3;

        xp += 4 * X_STRIDE;
        op += 4 * STRIDE_EL;
    }
}

extern "C" void kernel_launch(void* const* d_in, const int* in_sizes, int n_in,
                              void* d_out, int out_size, void* d_ws, size_t ws_size,
                              hipStream_t stream) {
    const float* x = (const float*)d_in[0];
    const float* w = (const float*)d_in[1];
    const float* b = (const float*)d_in[2];
    float* out = (float*)d_out;

    dim3 grid(2048), block(256);
    time2vec_kernel<<<grid, block, 0, stream>>>(x, w, b, out);
}